// Round 3
// baseline (322.980 us; speedup 1.0000x reference)
//
#include <hip/hip_runtime.h>
#include <math.h>

#define VOCAB   5000
#define T_CTC   512
#define S_TGT   128
#define BATCH   16
#define ALPHA_W 0.2f
#define CONF    0.9f            // 1 - smoothing
#define OFFV    (0.1f / 4999.0f)
#define CSTR    132             // compact row stride (floats): 129 used, 16B-aligned
#define ATT_N   (BATCH * S_TGT) // 2048 attention rows
#define WS_OFF  4096            // compact buffer starts at ws + 4096 floats (16 KB)
#define TCH     16              // t-rows per gather block
#define GATHER_BLKS (BATCH * (T_CTC / TCH))   // 512
#define CTR_IDX (ATT_N + BATCH)               // int slot for last-block ticket (2064)
#define B_BLKS  (BATCH + ATT_N)               // 2064 blocks in kernel B

// ---------------------------------------------------------------------------
// DPP wave_shr:1 on a double: lane k receives lane k-1's value, lane 0 gets 0.
// VALU-only (~4 cy) replacement for __shfl_up (2x ds_bpermute + lgkmcnt wait).
// ---------------------------------------------------------------------------
__device__ __forceinline__ double dpp_shr1(double x)
{
    const int lo  = __double2loint(x);
    const int hi  = __double2hiint(x);
    const int slo = __builtin_amdgcn_update_dpp(0, lo, 0x138, 0xF, 0xF, true);
    const int shi = __builtin_amdgcn_update_dpp(0, hi, 0x138, 0xF, 0xF, true);
    return __hiloint2double(shi, slo);
}

// ---------------------------------------------------------------------------
// Kernel A: scattered gather (line-granular, ~55-90 MB touched — measured
// cheaper than streaming all 164 MB by ~12 us). MLP-restructured: each thread
// owns one column-slot and hoists all 8 pick-loads into registers before any
// store, so 8 scattered loads are in flight per thread.
// Block 0 also zeroes the last-block ticket counter for kernel B.
// ---------------------------------------------------------------------------
__global__ __launch_bounds__(256)
void gather_kernel(const float* __restrict__ ctc, const int* __restrict__ tgt,
                   float* __restrict__ ws)
{
    if (blockIdx.x == 0 && threadIdx.x == 0)
        ((int*)ws)[CTR_IDX] = 0;            // poison-filled ws: must re-zero each iter

    const int b = blockIdx.x >> 5;          // 32 chunks per batch
    const int c = blockIdx.x & 31;          // chunk of 16 t-rows

    __shared__ int tg[S_TGT];
    if (threadIdx.x < S_TGT) tg[threadIdx.x] = tgt[b * S_TGT + threadIdx.x];
    __syncthreads();

    const float* lp   = ctc + ((size_t)b * T_CTC + (size_t)c * TCH) * VOCAB;
    float*       cbuf = ws + WS_OFF + ((size_t)b * T_CTC + (size_t)c * TCH) * CSTR;

    for (int v = threadIdx.x; v < 258; v += 256) {   // threads 0,1 take v=256,257
        const int tt0 = (v < 129) ? 0 : 1;           // even / odd rows of each pair
        const int idx = (v < 129) ? v : v - 129;
        const int col = (idx < S_TGT) ? tg[idx] : 0; // 128 -> blank
        float val[TCH / 2];
        #pragma unroll
        for (int p = 0; p < TCH / 2; ++p)            // 8 independent loads in flight
            val[p] = lp[(size_t)(2 * p + tt0) * VOCAB + col];
        #pragma unroll
        for (int p = 0; p < TCH / 2; ++p)
            cbuf[(size_t)(2 * p + tt0) * CSTR + idx] = val[p];
    }
}

// ---------------------------------------------------------------------------
// CTC chain helpers: 16-step register-prefetch + pure-VALU serial chain.
// ---------------------------------------------------------------------------
__device__ __forceinline__ void prefetch16(const float* __restrict__ cbuf,
                                           int base, int k, float2* E, float* Z)
{
    #pragma unroll
    for (int i = 0; i < 16; ++i) {
        int t = base + i;
        t = (t < T_CTC) ? t : (T_CTC - 1);          // clamp (clamped steps are guarded out)
        const float* row = cbuf + (size_t)t * CSTR;
        E[i] = *reinterpret_cast<const float2*>(row + 2 * k);  // 512B/wave, coalesced
        Z[i] = row[S_TGT];                                      // blank col, 1 line/wave
    }
}

template<bool TAIL>
__device__ __forceinline__ void run16(const float2* E, const float* Z, int base,
                                      double& b0, double& b1, double& b2,
                                      double& b3, double& b4, double& M,
                                      const double g1, const double g3)
{
    #pragma unroll
    for (int i = 0; i < 16; ++i) {
        if (TAIL && (base + i >= T_CTC)) return;     // uniform scalar branch
        const float  e0 = Z[i];
        const double X1 = (double)__expf(E[i].x - e0);   // off-chain, fills issue slots
        const double X3 = (double)__expf(E[i].y - e0);
        const double p3 = dpp_shr1(b3);                  // lane k-1's state 4k-1
        const double n0 = b0 + p3;
        const double n1 = (b1 + b0 + g1 * p3) * X1;
        const double n2 = b2 + b1;
        const double n3 = (b3 + b2 + g3 * b1) * X3;
        const double n4 = b4 + b3;
        b0 = n0; b1 = n1; b2 = n2; b3 = n3; b4 = n4;
        M += (double)e0;
    }
}

// ---------------------------------------------------------------------------
// Kernel B: blocks 0..15 = CTC recursion (wave 0 only, no LDS in chain path,
// double-buffered register prefetch from compact buffer). Blocks 16..2063 =
// one label-smoothing att row each. The LAST block to finish (device-scope
// atomic ticket) performs the final deterministic reduction — bit-identical
// math to the old combine kernel, one launch fewer.
// ---------------------------------------------------------------------------
__global__ __launch_bounds__(256)
void ctc_att_kernel(const int* __restrict__ tgt, const float* __restrict__ att,
                    float* __restrict__ ws, float* __restrict__ out)
{
    __shared__ float wsum[4];
    __shared__ int   isLast;
    const int tid = threadIdx.x;

    if (blockIdx.x >= BATCH) {
        // ---- label-smoothing row ----
        const int rr = blockIdx.x - BATCH;              // 0..2047
        const float* row = att + (size_t)rr * VOCAB;
        const float4* row4 = (const float4*)row;        // 1250 float4 exact

        float sum = 0.0f;
        for (int i = tid; i < VOCAB / 4; i += 256) {
            float4 v = row4[i];
            sum += v.x + v.y + v.z + v.w;
        }
        #pragma unroll
        for (int off = 32; off > 0; off >>= 1)
            sum += __shfl_down(sum, off, 64);

        if ((tid & 63) == 0) wsum[tid >> 6] = sum;
        __syncthreads();
        if (tid == 0) {
            const float rs = wsum[0] + wsum[1] + wsum[2] + wsum[3];
            const float tl = row[tgt[rr]];
            ws[rr] = -(CONF * tl + OFFV * (rs - tl));   // per-row partial, no atomic
        }
    } else if (tid < 64) {
        // ---- CTC chain (one wave) ----
        const int b = blockIdx.x;
        const int k = tid;                              // lane owns states 4k..4k+3
        const int*   tg   = tgt + b * S_TGT;
        const float* cbuf = ws + WS_OFF + (size_t)b * T_CTC * CSTR;

        const int t1 = tg[2 * k];
        const int t3 = tg[2 * k + 1];
        const int tp = (k > 0) ? tg[2 * k - 1] : 0;
        const double g1 = ((k > 0) && (t1 != 0) && (t1 != tp)) ? 1.0 : 0.0;
        const double g3 = ((t3 != 0) && (t3 != t1)) ? 1.0 : 0.0;

        const float e00 = cbuf[S_TGT];                  // t=0 blank
        double M  = (double)e00;
        double b0 = (k == 0) ? 1.0 : 0.0;
        double b1 = (k == 0) ? (double)__expf(cbuf[0] - e00) : 0.0;
        double b2 = 0.0, b3 = 0.0, b4 = 0.0;

        float2 EA[16], EB[16];
        float  ZA[16], ZB[16];

        prefetch16(cbuf, 1, k, EA, ZA);
        for (int h2 = 0; h2 < 16; ++h2) {               // 2 x 16 steps per iter
            const int base0 = 1 + 32 * h2;
            prefetch16(cbuf, base0 + 16, k, EB, ZB);    // in flight during EA chain
            run16<false>(EA, ZA, base0, b0, b1, b2, b3, b4, M, g1, g3);
            if (h2 < 15) {
                prefetch16(cbuf, base0 + 32, k, EA, ZA); // in flight during EB chain
                run16<false>(EB, ZB, base0 + 16, b0, b1, b2, b3, b4, M, g1, g3);
            } else {
                run16<true>(EB, ZB, base0 + 16, b0, b1, b2, b3, b4, M, g1, g3);
            }
        }

        if (k == 63) {
            const double bsum = b3 + b4;                // states 255, 256
            const double ll   = M + log(bsum);          // bsum==0 -> -inf
            float loss_b = (float)(-ll);
            if (!(loss_b <= 1e20f)) loss_b = 0.0f;      // zero_infinity (inf/NaN -> 0)
            ws[ATT_N + b] = loss_b;                     // per-batch slot, no atomic
        }
    }

    // ---- last-block-done fused combine (deterministic, same math as before) ----
    __syncthreads();                                    // block's partial store issued
    if (tid == 0) {
        __threadfence();                                // release: partial visible
        const int r = atomicAdd((int*)ws + CTR_IDX, 1); // device-scope
        isLast = (r == B_BLKS - 1);
    }
    __syncthreads();
    if (!isLast) return;
    __threadfence();                                    // acquire

    float s_att = 0.0f;
    for (int i = tid; i < ATT_N; i += 256) s_att += ws[i];
    float s_ctc = (tid < BATCH) ? ws[ATT_N + tid] : 0.0f;

    #pragma unroll
    for (int off = 32; off > 0; off >>= 1) {
        s_att += __shfl_down(s_att, off, 64);
        s_ctc += __shfl_down(s_ctc, off, 64);
    }
    __shared__ float wa[4], wc[4];
    if ((tid & 63) == 0) { wa[tid >> 6] = s_att; wc[tid >> 6] = s_ctc; }
    __syncthreads();
    if (tid == 0) {
        const float inv = 1.0f / (float)ATT_N;          // both sums / 2048
        const float a = (wa[0] + wa[1] + wa[2] + wa[3]) * inv;
        const float c = (wc[0] + wc[1] + wc[2] + wc[3]) * inv;
        out[0] = ALPHA_W * a + (1.0f - ALPHA_W) * c;
    }
}

extern "C" void kernel_launch(void* const* d_in, const int* in_sizes, int n_in,
                              void* d_out, int out_size, void* d_ws, size_t ws_size,
                              hipStream_t stream)
{
    const float* att = (const float*)d_in[0];
    const float* ctc = (const float*)d_in[1];
    const int*   tgt = (const int*)d_in[2];
    float* out = (float*)d_out;
    float* ws  = (float*)d_ws;

    gather_kernel<<<GATHER_BLKS, 256, 0, stream>>>(ctc, tgt, ws);
    ctc_att_kernel<<<BATCH + ATT_N, 256, 0, stream>>>(tgt, att, ws, out);
}

// Round 4
// 279.202 us; speedup vs baseline: 1.1568x; 1.1568x over previous
//
#include <hip/hip_runtime.h>
#include <math.h>

#define VOCAB   5000
#define T_CTC   512
#define S_TGT   128
#define BATCH   16
#define ALPHA_W 0.2f
#define CONF    0.9f            // 1 - smoothing
#define OFFV    (0.1f / 4999.0f)
#define CSTR    132             // compact row stride (floats): 129 used, 16B-aligned
#define ATT_N   (BATCH * S_TGT) // 2048 attention rows
#define WS_OFF  4096            // compact buffer starts at ws + 4096 floats (16 KB)
#define TCH     16              // t-rows per gather block
#define GATHER_BLKS (BATCH * (T_CTC / TCH))   // 512

// ---------------------------------------------------------------------------
// DPP wave_shr:1 on a double: lane k receives lane k-1's value, lane 0 gets 0.
// VALU-only replacement for __shfl_up (2x ds_bpermute + lgkmcnt wait).
// ---------------------------------------------------------------------------
__device__ __forceinline__ double dpp_shr1(double x)
{
    const int lo  = __double2loint(x);
    const int hi  = __double2hiint(x);
    const int slo = __builtin_amdgcn_update_dpp(0, lo, 0x138, 0xF, 0xF, true);
    const int shi = __builtin_amdgcn_update_dpp(0, hi, 0x138, 0xF, 0xF, true);
    return __hiloint2double(shi, slo);
}

// ---------------------------------------------------------------------------
// Kernel A: scattered gather (line-granular). Each thread owns one column-slot
// and hoists all 8 pick-loads into registers before any store (8 loads in
// flight per thread).
// ---------------------------------------------------------------------------
__global__ __launch_bounds__(256)
void gather_kernel(const float* __restrict__ ctc, const int* __restrict__ tgt,
                   float* __restrict__ ws)
{
    const int b = blockIdx.x >> 5;          // 32 chunks per batch
    const int c = blockIdx.x & 31;          // chunk of 16 t-rows

    __shared__ int tg[S_TGT];
    if (threadIdx.x < S_TGT) tg[threadIdx.x] = tgt[b * S_TGT + threadIdx.x];
    __syncthreads();

    const float* lp   = ctc + ((size_t)b * T_CTC + (size_t)c * TCH) * VOCAB;
    float*       cbuf = ws + WS_OFF + ((size_t)b * T_CTC + (size_t)c * TCH) * CSTR;

    for (int v = threadIdx.x; v < 258; v += 256) {   // threads 0,1 take v=256,257
        const int tt0 = (v < 129) ? 0 : 1;           // even / odd rows of each pair
        const int idx = (v < 129) ? v : v - 129;
        const int col = (idx < S_TGT) ? tg[idx] : 0; // 128 -> blank
        float val[TCH / 2];
        #pragma unroll
        for (int p = 0; p < TCH / 2; ++p)            // 8 independent loads in flight
            val[p] = lp[(size_t)(2 * p + tt0) * VOCAB + col];
        #pragma unroll
        for (int p = 0; p < TCH / 2; ++p)
            cbuf[(size_t)(2 * p + tt0) * CSTR + idx] = val[p];
    }
}

// ---------------------------------------------------------------------------
// CTC chain helpers: 16-step register-prefetch + pure-VALU serial chain.
// NOTE: these buffers MUST live in VGPRs — see __launch_bounds__(256,2) below.
// ---------------------------------------------------------------------------
__device__ __forceinline__ void prefetch16(const float* __restrict__ cbuf,
                                           int base, int k, float2* E, float* Z)
{
    #pragma unroll
    for (int i = 0; i < 16; ++i) {
        int t = base + i;
        t = (t < T_CTC) ? t : (T_CTC - 1);          // clamp (clamped steps are guarded out)
        const float* row = cbuf + (size_t)t * CSTR;
        E[i] = *reinterpret_cast<const float2*>(row + 2 * k);  // 512B/wave, coalesced
        Z[i] = row[S_TGT];                                      // blank col, 1 line/wave
    }
}

template<bool TAIL>
__device__ __forceinline__ void run16(const float2* E, const float* Z, int base,
                                      double& b0, double& b1, double& b2,
                                      double& b3, double& b4, double& M,
                                      const double g1, const double g3)
{
    #pragma unroll
    for (int i = 0; i < 16; ++i) {
        if (TAIL && (base + i >= T_CTC)) return;     // uniform scalar branch
        const float  e0 = Z[i];
        const double X1 = (double)__expf(E[i].x - e0);   // off-chain, fills issue slots
        const double X3 = (double)__expf(E[i].y - e0);
        const double p3 = dpp_shr1(b3);                  // lane k-1's state 4k-1
        const double n0 = b0 + p3;
        const double n1 = (b1 + b0 + g1 * p3) * X1;
        const double n2 = b2 + b1;
        const double n3 = (b3 + b2 + g3 * b1) * X3;
        const double n4 = b4 + b3;
        b0 = n0; b1 = n1; b2 = n2; b3 = n3; b4 = n4;
        M += (double)e0;
    }
}

// ---------------------------------------------------------------------------
// Kernel B: blocks 0..15 = CTC recursion (wave 0 only), blocks 16..2063 = one
// label-smoothing att row each (BW work overlapping the latency-bound chain).
// __launch_bounds__(256, 2): min 2 waves/SIMD -> up to 256 VGPRs, so the
// 96-reg prefetch double-buffer stays in registers. Round 3 measured the
// default heuristic allocating 64 VGPRs -> buffers in SCRATCH -> the chain
// was scratch-latency-bound at ~100 us (VALUBusy 1.2%).
// ---------------------------------------------------------------------------
__global__ __launch_bounds__(256, 2)
void ctc_att_kernel(const int* __restrict__ tgt, const float* __restrict__ att,
                    float* __restrict__ ws)
{
    if (blockIdx.x >= BATCH) {
        // ---- label-smoothing row ----
        const int rr = blockIdx.x - BATCH;              // 0..2047
        const float* row = att + (size_t)rr * VOCAB;
        const float4* row4 = (const float4*)row;        // 1250 float4 exact

        float sum = 0.0f;
        for (int i = threadIdx.x; i < VOCAB / 4; i += 256) {
            float4 v = row4[i];
            sum += v.x + v.y + v.z + v.w;
        }
        #pragma unroll
        for (int off = 32; off > 0; off >>= 1)
            sum += __shfl_down(sum, off, 64);

        __shared__ float wsum[4];
        if ((threadIdx.x & 63) == 0) wsum[threadIdx.x >> 6] = sum;
        __syncthreads();
        if (threadIdx.x == 0) {
            const float rs = wsum[0] + wsum[1] + wsum[2] + wsum[3];
            const float tl = row[tgt[rr]];
            ws[rr] = -(CONF * tl + OFFV * (rs - tl));   // per-row partial, no atomic
        }
        return;
    }

    if (threadIdx.x >= 64) return;                      // chain runs on wave 0 only
    const int b = blockIdx.x;
    const int k = threadIdx.x;                          // lane owns states 4k..4k+3
    const int*   tg   = tgt + b * S_TGT;
    const float* cbuf = ws + WS_OFF + (size_t)b * T_CTC * CSTR;

    const int t1 = tg[2 * k];
    const int t3 = tg[2 * k + 1];
    const int tp = (k > 0) ? tg[2 * k - 1] : 0;
    const double g1 = ((k > 0) && (t1 != 0) && (t1 != tp)) ? 1.0 : 0.0;
    const double g3 = ((t3 != 0) && (t3 != t1)) ? 1.0 : 0.0;

    const float e00 = cbuf[S_TGT];                      // t=0 blank
    double M  = (double)e00;
    double b0 = (k == 0) ? 1.0 : 0.0;
    double b1 = (k == 0) ? (double)__expf(cbuf[0] - e00) : 0.0;
    double b2 = 0.0, b3 = 0.0, b4 = 0.0;

    float2 EA[16], EB[16];
    float  ZA[16], ZB[16];

    prefetch16(cbuf, 1, k, EA, ZA);
    for (int h2 = 0; h2 < 16; ++h2) {                   // 2 x 16 steps per iter
        const int base0 = 1 + 32 * h2;
        prefetch16(cbuf, base0 + 16, k, EB, ZB);        // in flight during EA chain
        run16<false>(EA, ZA, base0, b0, b1, b2, b3, b4, M, g1, g3);
        if (h2 < 15) {
            prefetch16(cbuf, base0 + 32, k, EA, ZA);    // in flight during EB chain
            run16<false>(EB, ZB, base0 + 16, b0, b1, b2, b3, b4, M, g1, g3);
        } else {
            run16<true>(EB, ZB, base0 + 16, b0, b1, b2, b3, b4, M, g1, g3);
        }
    }

    if (k == 63) {
        const double bsum = b3 + b4;                    // states 255, 256
        const double ll   = M + log(bsum);              // bsum==0 -> -inf
        float loss_b = (float)(-ll);
        if (!(loss_b <= 1e20f)) loss_b = 0.0f;          // zero_infinity (inf/NaN -> 0)
        ws[ATT_N + b] = loss_b;                         // per-batch slot, no atomic
    }
}

// ---------------------------------------------------------------------------
// Kernel C: final reduction of 2048 att partials + 16 ctc losses.
// ---------------------------------------------------------------------------
__global__ __launch_bounds__(256)
void combine_kernel(const float* __restrict__ ws, float* __restrict__ out)
{
    const int tid = threadIdx.x;
    float s_att = 0.0f;
    for (int i = tid; i < ATT_N; i += 256) s_att += ws[i];
    float s_ctc = (tid < BATCH) ? ws[ATT_N + tid] : 0.0f;

    #pragma unroll
    for (int off = 32; off > 0; off >>= 1) {
        s_att += __shfl_down(s_att, off, 64);
        s_ctc += __shfl_down(s_ctc, off, 64);
    }
    __shared__ float wa[4], wc[4];
    if ((tid & 63) == 0) { wa[tid >> 6] = s_att; wc[tid >> 6] = s_ctc; }
    __syncthreads();
    if (tid == 0) {
        const float inv = 1.0f / (float)ATT_N;          // both sums / 2048
        const float a = (wa[0] + wa[1] + wa[2] + wa[3]) * inv;
        const float c = (wc[0] + wc[1] + wc[2] + wc[3]) * inv;
        out[0] = ALPHA_W * a + (1.0f - ALPHA_W) * c;
    }
}

extern "C" void kernel_launch(void* const* d_in, const int* in_sizes, int n_in,
                              void* d_out, int out_size, void* d_ws, size_t ws_size,
                              hipStream_t stream)
{
    const float* att = (const float*)d_in[0];
    const float* ctc = (const float*)d_in[1];
    const int*   tgt = (const int*)d_in[2];
    float* out = (float*)d_out;
    float* ws  = (float*)d_ws;

    gather_kernel<<<GATHER_BLKS, 256, 0, stream>>>(ctc, tgt, ws);
    ctc_att_kernel<<<BATCH + ATT_N, 256, 0, stream>>>(tgt, att, ws);
    combine_kernel<<<1, 256, 0, stream>>>(ws, out);
}